// Round 1
// baseline (5325.035 us; speedup 1.0000x reference)
//
#include <hip/hip_runtime.h>
#include <math.h>

#define BB 128
#define TT 2048
#define II 128
#define UU 256
#define OO 128

// LDS-only barrier: orders LDS ops across the block WITHOUT draining vmcnt
// (global stores stay in flight; prefetch loads waited at use). Rule-18 idiom:
// sched_barrier(0) on both sides pins memory-op ordering around s_barrier.
__device__ __forceinline__ void bar_lds() {
    __builtin_amdgcn_sched_barrier(0);
    asm volatile("s_waitcnt lgkmcnt(0)" ::: "memory");
    __builtin_amdgcn_s_barrier();
    __builtin_amdgcn_sched_barrier(0);
}

// ---------------- Kernel 1: input projection ----------------
// xp[row, u] = sum_i x[row, i] * W_ih[u, i] + (b_ih[u] + b_hh[u])
// rows = b*T + t, written into the hs region of d_out (consumed by k_rnn).
__global__ __launch_bounds__(256) void k_inproj(
    const float* __restrict__ x, const float* __restrict__ Wih,
    const float* __restrict__ bih, const float* __restrict__ bhh,
    float* __restrict__ xp)
{
    __shared__ __align__(16) float xs[64 * II];   // 32 KB row tile
    const int tid = threadIdx.x;                  // tid == output unit u
    float w[II];
    #pragma unroll
    for (int j = 0; j < II; j += 4) {
        float4 v = *reinterpret_cast<const float4*>(&Wih[tid * II + j]);
        w[j] = v.x; w[j + 1] = v.y; w[j + 2] = v.z; w[j + 3] = v.w;
    }
    const float bias = bih[tid] + bhh[tid];
    const int ntiles = (BB * TT) / 64;            // 4096
    for (int tile = blockIdx.x; tile < ntiles; tile += gridDim.x) {
        const size_t rowbase = (size_t)tile * 64;
        const float4* xg = reinterpret_cast<const float4*>(x + rowbase * II);
        float4* xs4 = reinterpret_cast<float4*>(xs);
        #pragma unroll
        for (int i = 0; i < 8; ++i) xs4[tid + i * 256] = xg[tid + i * 256];
        __syncthreads();
        for (int r = 0; r < 64; ++r) {
            float a0 = 0.f, a1 = 0.f, a2 = 0.f, a3 = 0.f;
            #pragma unroll
            for (int j = 0; j < II; j += 4) {
                float4 hv = *reinterpret_cast<const float4*>(&xs[r * II + j]);
                a0 += w[j] * hv.x;     a1 += w[j + 1] * hv.y;
                a2 += w[j + 2] * hv.z; a3 += w[j + 3] * hv.w;
            }
            xp[(rowbase + r) * UU + tid] = bias + ((a0 + a1) + (a2 + a3));
        }
        __syncthreads();
    }
}

// ---------------- Kernel 2: serial recurrence ----------------
// One block per batch element. 512 threads: thread (u = tid&255, kk = tid>>8)
// holds W_hh[u, kk*128 .. kk*128+127] in 128 VGPRs. h (masked) lives in LDS.
// Reads xp[b,t,:] from the hs region and overwrites it with h_raw (unmasked);
// k_readout later consumes h_raw and applies the {3,7} mask in place.
__global__ __launch_bounds__(512) void k_rnn(
    const float* __restrict__ Whh, float* __restrict__ xph)
{
    __shared__ __align__(16) float hcur[UU];
    __shared__ __align__(16) float part[2][UU];
    const int tid = threadIdx.x;
    const int u  = tid & 255;
    const int kk = tid >> 8;
    float w[128];
    #pragma unroll
    for (int j = 0; j < 128; j += 4) {
        float4 v = *reinterpret_cast<const float4*>(&Whh[u * UU + kk * 128 + j]);
        w[j] = v.x; w[j + 1] = v.y; w[j + 2] = v.z; w[j + 3] = v.w;
    }
    if (tid < UU) hcur[tid] = 0.f;
    __syncthreads();

    float* rowp = xph + (size_t)blockIdx.x * TT * UU;
    float xpv = rowp[u];                       // xp[t=0] (both halves load it)
    for (int t = 0; t < TT; ++t) {
        float xpn = 0.f;
        if (t + 1 < TT) xpn = rowp[(size_t)(t + 1) * UU + u];   // prefetch
        float a0 = 0.f, a1 = 0.f, a2 = 0.f, a3 = 0.f;
        #pragma unroll
        for (int j = 0; j < 128; j += 4) {
            float4 hv = *reinterpret_cast<const float4*>(&hcur[kk * 128 + j]);
            a0 += w[j] * hv.x;     a1 += w[j + 1] * hv.y;
            a2 += w[j + 2] * hv.z; a3 += w[j + 3] * hv.w;
        }
        part[kk][u] = (a0 + a1) + (a2 + a3);
        bar_lds();
        // both halves redundantly finish the sum (balances post-barrier work)
        {
            float s = part[0][u] + part[1][u] + xpv;
            // tanh(s) = 1 - 2/(exp(2s)+1); abs err ~1e-7, saturates correctly
            float hr = 1.0f - 2.0f / (__expf(2.0f * s) + 1.0f);
            if (kk == 0) {
                rowp[(size_t)t * UU + u] = hr;               // h_raw out
            } else {
                hcur[u] = (u == 3 || u == 7) ? 0.f : hr;     // masked carry
            }
        }
        bar_lds();
        xpv = xpn;
    }
}

// ---------------- Kernel 3: readout + mask fix-up ----------------
// readout[row, o] = sum_u h_raw[row, u] * W_fc[o, u] + b_fc[o]
// then zero h_raw[row, {3,7}] in place so the hs output is the masked one.
__global__ __launch_bounds__(256) void k_readout(
    const float* __restrict__ Wfc, const float* __restrict__ bfc,
    float* __restrict__ hraw, float* __restrict__ outR)
{
    __shared__ __align__(16) float hs[32 * UU];        // 32 KB
    __shared__ __align__(16) float part[2][32 * OO];   // 32 KB
    const int tid = threadIdx.x;
    const int o  = tid & 127;
    const int kk = tid >> 7;
    float w[128];
    #pragma unroll
    for (int j = 0; j < 128; j += 4) {
        float4 v = *reinterpret_cast<const float4*>(&Wfc[o * UU + kk * 128 + j]);
        w[j] = v.x; w[j + 1] = v.y; w[j + 2] = v.z; w[j + 3] = v.w;
    }
    const float bias = (kk == 0) ? bfc[o] : 0.f;
    const int ntiles = (BB * TT) / 32;                 // 8192
    for (int tile = blockIdx.x; tile < ntiles; tile += gridDim.x) {
        const size_t rowbase = (size_t)tile * 32;
        const float4* hg = reinterpret_cast<const float4*>(hraw + rowbase * UU);
        float4* hs4 = reinterpret_cast<float4*>(hs);
        #pragma unroll
        for (int i = 0; i < 8; ++i) hs4[tid + i * 256] = hg[tid + i * 256];
        __syncthreads();
        // raw values are safely staged in LDS: zero killed units in global hs
        if (tid < 64) {
            int r = tid >> 1, c = (tid & 1) ? 7 : 3;
            hraw[(rowbase + r) * UU + c] = 0.f;
        }
        for (int r = 0; r < 32; ++r) {
            float a0 = 0.f, a1 = 0.f, a2 = 0.f, a3 = 0.f;
            #pragma unroll
            for (int j = 0; j < 128; j += 4) {
                float4 hv = *reinterpret_cast<const float4*>(&hs[r * UU + kk * 128 + j]);
                a0 += w[j] * hv.x;     a1 += w[j + 1] * hv.y;
                a2 += w[j + 2] * hv.z; a3 += w[j + 3] * hv.w;
            }
            part[kk][r * OO + o] = bias + (a0 + a1) + (a2 + a3);
        }
        __syncthreads();
        const float4* p0 = reinterpret_cast<const float4*>(part[0]);
        const float4* p1 = reinterpret_cast<const float4*>(part[1]);
        float4* og = reinterpret_cast<float4*>(outR + rowbase * OO);
        #pragma unroll
        for (int i = 0; i < 4; ++i) {
            int idx = tid + i * 256;     // 1024 float4 = 32 rows x 128 o
            float4 v0 = p0[idx], v1 = p1[idx];
            float4 r;
            r.x = v0.x + v1.x; r.y = v0.y + v1.y;
            r.z = v0.z + v1.z; r.w = v0.w + v1.w;
            og[idx] = r;
        }
        __syncthreads();
    }
}

extern "C" void kernel_launch(void* const* d_in, const int* in_sizes, int n_in,
                              void* d_out, int out_size, void* d_ws, size_t ws_size,
                              hipStream_t stream) {
    const float* x   = (const float*)d_in[0];
    const float* Wih = (const float*)d_in[1];
    const float* Whh = (const float*)d_in[2];
    const float* bih = (const float*)d_in[3];
    const float* bhh = (const float*)d_in[4];
    const float* Wfc = (const float*)d_in[5];
    const float* bfc = (const float*)d_in[6];
    float* outR = (float*)d_out;                       // readouts [B,T,O]
    float* outH = outR + (size_t)BB * TT * OO;         // hs       [B,T,U]

    k_inproj<<<512, 256, 0, stream>>>(x, Wih, bih, bhh, outH);
    k_rnn<<<128, 512, 0, stream>>>(Whh, outH);
    k_readout<<<512, 256, 0, stream>>>(Wfc, bfc, outH, outR);
}

// Round 2
// 1732.630 us; speedup vs baseline: 3.0734x; 3.0734x over previous
//
#include <hip/hip_runtime.h>
#include <math.h>

#define BB 128
#define TT 2048
#define II 128
#define UU 256
#define OO 128

// LDS-only barrier: orders LDS ops without draining vmcnt (global stores /
// prefetch loads stay in flight). sched_barrier(0) pins ordering (rule 18).
__device__ __forceinline__ void bar_lds() {
    __builtin_amdgcn_sched_barrier(0);
    asm volatile("s_waitcnt lgkmcnt(0)" ::: "memory");
    __builtin_amdgcn_s_barrier();
    __builtin_amdgcn_sched_barrier(0);
}

__device__ __forceinline__ void fma4(float4& a, const float4 w, const float4 h) {
    a.x = fmaf(w.x, h.x, a.x);
    a.y = fmaf(w.y, h.y, a.y);
    a.z = fmaf(w.z, h.z, a.z);
    a.w = fmaf(w.w, h.w, a.w);
}

// ---------------- Kernel 1: input projection ----------------
// xp[row,u] = x[row,:] . W_ih[u,:] + b_ih[u] + b_hh[u]
// 512 thr: kk=tid&3 (32-float k-chunk), uo=tid>>2 owns u rows uo*2,uo*2+1.
// x tile staged in LDS with chunk-swizzle (row stride 160, chunk stride 40)
// so the 4 kk addresses per read hit distinct bank groups.
__global__ __launch_bounds__(512, 2) void k_inproj(
    const float* __restrict__ x, const float* __restrict__ Wih,
    const float* __restrict__ bih, const float* __restrict__ bhh,
    float* __restrict__ xp)
{
    __shared__ __align__(16) float xs[64 * 160];   // 40 KB
    const int tid = threadIdx.x;
    const int kk = tid & 3;
    const int uo = tid >> 2;
    const int u0 = uo * 2;
    float4 w0[8], w1[8];
    #pragma unroll
    for (int j = 0; j < 8; ++j) {
        w0[j] = *reinterpret_cast<const float4*>(&Wih[(size_t)u0 * II + kk * 32 + j * 4]);
        w1[j] = *reinterpret_cast<const float4*>(&Wih[(size_t)(u0 + 1) * II + kk * 32 + j * 4]);
    }
    const int uw = u0 + (kk & 1);
    const float bias = bih[uw] + bhh[uw];
    const int ntiles = (BB * TT) / 64;             // 4096
    for (int tile = blockIdx.x; tile < ntiles; tile += gridDim.x) {
        const size_t rowbase = (size_t)tile * 64;
        const float4* xg = reinterpret_cast<const float4*>(x + rowbase * II);
        #pragma unroll
        for (int i = 0; i < 4; ++i) {
            int v = tid + i * 512;                 // 0..2047 float4s
            int row = v >> 5;
            int c = (v & 31) >> 3;
            int jj = v & 7;
            float4 val = xg[v];
            *reinterpret_cast<float4*>(&xs[row * 160 + c * 40 + jj * 4]) = val;
        }
        __syncthreads();
        for (int r = 0; r < 64; ++r) {
            const float4* hrow = reinterpret_cast<const float4*>(&xs[r * 160 + kk * 40]);
            float4 a0 = {0,0,0,0}, a1 = {0,0,0,0};
            #pragma unroll
            for (int j = 0; j < 8; ++j) {
                float4 hv = hrow[j];
                fma4(a0, w0[j], hv);
                fma4(a1, w1[j], hv);
            }
            float s0 = (a0.x + a0.y) + (a0.z + a0.w);
            float s1 = (a1.x + a1.y) + (a1.z + a1.w);
            // value-splitting butterfly over 4-lane group (2 values)
            float z = (kk & 1) ? s0 : s1;
            float rcvd = __shfl_xor(z, 1, 4);
            float A = ((kk & 1) ? s1 : s0) + rcvd;  // lane&1==0 -> s0, ==1 -> s1
            A += __shfl_xor(A, 2, 4);
            if (kk < 2) xp[(rowbase + r) * UU + uw] = A + bias;
        }
        __syncthreads();
    }
}

// ---------------- Kernel 2: serial recurrence ----------------
// 1 block/batch, 512 thr: kk=tid&7 (32-float k-chunk), ug=tid>>3 owns 4 u-rows.
// W_hh slice (4x32) in 128 VGPRs. h double-buffered in LDS (chunk stride 40).
// 8-lane value-splitting butterfly -> each lane finalizes one u; kk<4 lanes
// write h_raw to global, kk>=4 write masked h to LDS. ONE barrier per step.
__global__ __launch_bounds__(512, 2) void k_rnn(
    const float* __restrict__ Whh, float* __restrict__ xph)
{
    __shared__ __align__(16) float hc[2 * 320];    // 2 bufs x 8 chunks x 40
    const int tid = threadIdx.x;
    const int kk = tid & 7;
    const int ug = tid >> 3;
    const int u0 = ug * 4;
    float4 w[4][8];
    #pragma unroll
    for (int r = 0; r < 4; ++r)
        #pragma unroll
        for (int j = 0; j < 8; ++j)
            w[r][j] = *reinterpret_cast<const float4*>(
                &Whh[(size_t)(u0 + r) * UU + kk * 32 + j * 4]);
    const int r4 = kk & 3;
    const int uw = u0 + r4;                        // u this lane finalizes
    const bool isglob = (kk < 4);
    const bool kill = (uw == 3) || (uw == 7);
    const int wr_off = (uw >> 5) * 40 + (uw & 31); // LDS h slot for uw

    if (tid < 80) *reinterpret_cast<float4*>(&hc[tid * 4]) = (float4){0,0,0,0};
    __syncthreads();

    float* rowp = xph + (size_t)blockIdx.x * (size_t)TT * UU;
    float xpv = rowp[uw];
    float xpn = rowp[UU + uw];

    auto step = [&](int t, int p) {
        float xpn2 = 0.f;
        if (t + 2 < TT) xpn2 = rowp[(size_t)(t + 2) * UU + uw];
        const float4* hb = reinterpret_cast<const float4*>(&hc[p * 320 + kk * 40]);
        float4 a0 = {0,0,0,0}, a1 = {0,0,0,0}, a2 = {0,0,0,0}, a3 = {0,0,0,0};
        #pragma unroll
        for (int j = 0; j < 8; ++j) {
            float4 hv = hb[j];
            fma4(a0, w[0][j], hv); fma4(a1, w[1][j], hv);
            fma4(a2, w[2][j], hv); fma4(a3, w[3][j], hv);
        }
        float s0 = (a0.x + a0.y) + (a0.z + a0.w);
        float s1 = (a1.x + a1.y) + (a1.z + a1.w);
        float s2 = (a2.x + a2.y) + (a2.z + a2.w);
        float s3 = (a3.x + a3.y) + (a3.z + a3.w);
        // stage 1 (xor 1): evens own {s0,s2}, odds own {s1,s3}
        float za = (kk & 1) ? s0 : s1;
        float zb = (kk & 1) ? s2 : s3;
        float ra = __shfl_xor(za, 1, 8);
        float rb = __shfl_xor(zb, 1, 8);
        float A = ((kk & 1) ? s1 : s0) + ra;       // value index (kk&1)
        float Bv = ((kk & 1) ? s3 : s2) + rb;      // value index (kk&1)+2
        // stage 2 (xor 2): keep A if (kk&2)==0 else Bv
        float z2 = (kk & 2) ? A : Bv;
        float r2 = __shfl_xor(z2, 2, 8);
        float C = ((kk & 2) ? Bv : A) + r2;        // C = partial sum of s[r4]
        // stage 3 (xor 4)
        float D = C + __shfl_xor(C, 4, 8);         // D = s[r4], full
        float s = D + xpv;
        float hr = 1.0f - 2.0f / (__expf(2.0f * s) + 1.0f);
        if (isglob) {
            rowp[(size_t)t * UU + uw] = hr;                    // h_raw
        } else {
            hc[(p ^ 1) * 320 + wr_off] = kill ? 0.f : hr;      // masked carry
        }
        bar_lds();
        xpv = xpn; xpn = xpn2;
    };
    for (int t = 0; t < TT; t += 2) { step(t, 0); step(t + 1, 1); }
}

// ---------------- Kernel 3: readout + mask fix-up ----------------
// 256 thr: kk=tid&3 (64-float k-chunk), oo=tid>>2 owns o rows oo*2,oo*2+1.
// h_raw tile staged swizzled (row stride 288, chunk stride 72); after staging,
// zero killed cols {3,7} of global h_raw so the hs output is masked.
__global__ __launch_bounds__(256, 2) void k_readout(
    const float* __restrict__ Wfc, const float* __restrict__ bfc,
    float* __restrict__ hraw, float* __restrict__ outR)
{
    __shared__ __align__(16) float hs[64 * 288];   // 72 KB
    const int tid = threadIdx.x;
    const int kk = tid & 3;
    const int oo = tid >> 2;
    const int o0 = oo * 2;
    float4 w0[16], w1[16];
    #pragma unroll
    for (int j = 0; j < 16; ++j) {
        w0[j] = *reinterpret_cast<const float4*>(&Wfc[(size_t)o0 * UU + kk * 64 + j * 4]);
        w1[j] = *reinterpret_cast<const float4*>(&Wfc[(size_t)(o0 + 1) * UU + kk * 64 + j * 4]);
    }
    const int ow = o0 + (kk & 1);
    const float bias = bfc[ow];
    const int ntiles = (BB * TT) / 64;             // 4096
    for (int tile = blockIdx.x; tile < ntiles; tile += gridDim.x) {
        const size_t rowbase = (size_t)tile * 64;
        const float4* hg = reinterpret_cast<const float4*>(hraw + rowbase * UU);
        #pragma unroll
        for (int i = 0; i < 16; ++i) {
            int v = tid + i * 256;                 // 0..4095 float4s
            int row = v >> 6;
            int c = (v & 63) >> 4;
            int jj = v & 15;
            float4 val = hg[v];
            *reinterpret_cast<float4*>(&hs[row * 288 + c * 72 + jj * 4]) = val;
        }
        __syncthreads();
        // raw values staged: zero killed units in the global hs output
        if (tid < 128) {
            int r = tid >> 1, c = (tid & 1) ? 7 : 3;
            hraw[(rowbase + r) * UU + c] = 0.f;
        }
        for (int r = 0; r < 64; ++r) {
            const float4* hrow = reinterpret_cast<const float4*>(&hs[r * 288 + kk * 72]);
            float4 a0 = {0,0,0,0}, a1 = {0,0,0,0};
            #pragma unroll
            for (int j = 0; j < 16; ++j) {
                float4 hv = hrow[j];
                fma4(a0, w0[j], hv);
                fma4(a1, w1[j], hv);
            }
            float s0 = (a0.x + a0.y) + (a0.z + a0.w);
            float s1 = (a1.x + a1.y) + (a1.z + a1.w);
            float z = (kk & 1) ? s0 : s1;
            float rcvd = __shfl_xor(z, 1, 4);
            float A = ((kk & 1) ? s1 : s0) + rcvd;
            A += __shfl_xor(A, 2, 4);
            if (kk < 2) outR[(rowbase + r) * OO + ow] = A + bias;
        }
        __syncthreads();
    }
}

extern "C" void kernel_launch(void* const* d_in, const int* in_sizes, int n_in,
                              void* d_out, int out_size, void* d_ws, size_t ws_size,
                              hipStream_t stream) {
    const float* x   = (const float*)d_in[0];
    const float* Wih = (const float*)d_in[1];
    const float* Whh = (const float*)d_in[2];
    const float* bih = (const float*)d_in[3];
    const float* bhh = (const float*)d_in[4];
    const float* Wfc = (const float*)d_in[5];
    const float* bfc = (const float*)d_in[6];
    float* outR = (float*)d_out;                       // readouts [B,T,O]
    float* outH = outR + (size_t)BB * TT * OO;         // hs       [B,T,U]

    k_inproj<<<512, 512, 0, stream>>>(x, Wih, bih, bhh, outH);
    k_rnn<<<128, 512, 0, stream>>>(Whh, outH);
    k_readout<<<512, 256, 0, stream>>>(Wfc, bfc, outH, outR);
}

// Round 4
// 1616.109 us; speedup vs baseline: 3.2950x; 1.0721x over previous
//
#include <hip/hip_runtime.h>
#include <math.h>

#define BB 128
#define TT 2048
#define II 128
#define UU 256
#define OO 128

// LDS-only barrier: orders LDS ops without draining vmcnt (global stores /
// prefetch loads stay in flight). sched_barrier(0) pins ordering (rule 18).
__device__ __forceinline__ void bar_lds() {
    __builtin_amdgcn_sched_barrier(0);
    asm volatile("s_waitcnt lgkmcnt(0)" ::: "memory");
    __builtin_amdgcn_s_barrier();
    __builtin_amdgcn_sched_barrier(0);
}

__device__ __forceinline__ void fma4(float4& a, const float4 w, const float4 h) {
    a.x = fmaf(w.x, h.x, a.x);
    a.y = fmaf(w.y, h.y, a.y);
    a.z = fmaf(w.z, h.z, a.z);
    a.w = fmaf(w.w, h.w, a.w);
}

// DPP cross-lane exchanges (pure VALU, no LDS pipe):
__device__ __forceinline__ float dpp_xor1(float x) {   // quad_perm [1,0,3,2]
    return __int_as_float(__builtin_amdgcn_mov_dpp(__float_as_int(x), 0xB1, 0xF, 0xF, true));
}
__device__ __forceinline__ float dpp_xor2(float x) {   // quad_perm [2,3,0,1]
    return __int_as_float(__builtin_amdgcn_mov_dpp(__float_as_int(x), 0x4E, 0xF, 0xF, true));
}
__device__ __forceinline__ float dpp_xor8(float x) {   // row_ror:8 (xor8 in 16)
    return __int_as_float(__builtin_amdgcn_mov_dpp(__float_as_int(x), 0x128, 0xF, 0xF, true));
}
__device__ __forceinline__ float swz_xor4(float x) {   // ds_swizzle xor4
    return __int_as_float(__builtin_amdgcn_ds_swizzle(__float_as_int(x), 0x101F));
}

// 4-row value-splitting butterfly. CONTRACT: lane ends with the FULL sum of
// row (tid & 3) of this group (after xor over lane bits 0,1,3). s0..s3 are
// this lane's k-chunk partials for rows u0+0..3.
__device__ __forceinline__ float reduce4(float s0, float s1, float s2, float s3,
                                         int tid) {
    const bool e1 = (tid & 1), e2 = (tid & 2);
    float z0 = e1 ? s0 : s1;
    float z1 = e1 ? s2 : s3;
    float A0 = (e1 ? s1 : s0) + dpp_xor1(z0);   // row bit0
    float A1 = (e1 ? s3 : s2) + dpp_xor1(z1);   // row 2+bit0
    float z2 = e2 ? A0 : A1;
    float C = (e2 ? A1 : A0) + dpp_xor2(z2);    // row (tid&3)
    return C + dpp_xor8(C);                      // + other k-half (bit 3)
}

// ---------------- Kernel 1: input projection ----------------
// xp[row,u] = x[row,:] . W_ih[u,:] + b_ih[u] + b_hh[u]
// 512 thr: kk = lane bits {0,1,3} -> 8 chunks of 16 floats (K=128);
// G = 64 groups own 4 u each. Per row: 4 ds_read_b128 feed 16 fma4.
__global__ __launch_bounds__(512, 2) void k_inproj(
    const float* __restrict__ x, const float* __restrict__ Wih,
    const float* __restrict__ bih, const float* __restrict__ bhh,
    float* __restrict__ xp)
{
    __shared__ __align__(16) float xs[64 * 160];   // 64 rows x 8 chunks x 20
    const int tid = threadIdx.x;
    const int kk = (tid & 3) | ((tid >> 1) & 4);   // bits 0,1,3
    const int G  = ((tid >> 2) & 1) | ((tid >> 4) << 1);   // 0..63
    const int u0 = G * 4;
    float4 w[4][4];
    #pragma unroll
    for (int r = 0; r < 4; ++r)
        #pragma unroll
        for (int j = 0; j < 4; ++j)
            w[r][j] = *reinterpret_cast<const float4*>(
                &Wih[(size_t)(u0 + r) * II + kk * 16 + j * 4]);
    const int r3 = tid & 3;                        // matches reduce4 contract
    const int uw = u0 + r3;
    const float bias = bih[uw] + bhh[uw];
    const bool writer = (tid & 8) == 0;
    const int ntiles = (BB * TT) / 64;             // 4096
    for (int tile = blockIdx.x; tile < ntiles; tile += gridDim.x) {
        const size_t rowbase = (size_t)tile * 64;
        const float4* xg = reinterpret_cast<const float4*>(x + rowbase * II);
        #pragma unroll
        for (int i = 0; i < 4; ++i) {
            int v = tid + i * 512;                 // 0..2047 float4s
            int row = v >> 5, q = v & 31;
            float4 val = xg[v];
            *reinterpret_cast<float4*>(&xs[row * 160 + (q >> 2) * 20 + (q & 3) * 4]) = val;
        }
        __syncthreads();
        for (int r = 0; r < 64; ++r) {
            const float4* hrow = reinterpret_cast<const float4*>(&xs[r * 160 + kk * 20]);
            float4 a0 = {0,0,0,0}, a1 = {0,0,0,0}, a2 = {0,0,0,0}, a3 = {0,0,0,0};
            #pragma unroll
            for (int j = 0; j < 4; ++j) {
                float4 hv = hrow[j];
                fma4(a0, w[0][j], hv); fma4(a1, w[1][j], hv);
                fma4(a2, w[2][j], hv); fma4(a3, w[3][j], hv);
            }
            float s0 = (a0.x + a0.y) + (a0.z + a0.w);
            float s1 = (a1.x + a1.y) + (a1.z + a1.w);
            float s2 = (a2.x + a2.y) + (a2.z + a2.w);
            float s3 = (a3.x + a3.y) + (a3.z + a3.w);
            float D = reduce4(s0, s1, s2, s3, tid);
            if (writer) xp[(rowbase + r) * UU + uw] = D + bias;
        }
        __syncthreads();
    }
}

// ---------------- Kernel 2: serial recurrence ----------------
// 1 block/batch, 512 thr. kk = lane bits {0,1,3} -> 8 chunks of 32 floats
// (stride 36: banks 4*kk -> perfectly spread). G = 64 groups x 4 u rows.
// All-DPP reduce; bit3=1 lanes write h_raw to global, bit3=0 write masked LDS.
__global__ __launch_bounds__(512, 2) void k_rnn(
    const float* __restrict__ Whh, float* __restrict__ xph)
{
    __shared__ __align__(16) float hc[2 * 288];    // 2 bufs x 8 chunks x 36
    const int tid = threadIdx.x;
    const int kk = (tid & 3) | ((tid >> 1) & 4);   // bits 0,1,3
    const int G  = ((tid >> 2) & 1) | ((tid >> 4) << 1);   // 0..63
    const int u0 = G * 4;
    float4 w[4][8];
    #pragma unroll
    for (int r = 0; r < 4; ++r)
        #pragma unroll
        for (int j = 0; j < 8; ++j)
            w[r][j] = *reinterpret_cast<const float4*>(
                &Whh[(size_t)(u0 + r) * UU + kk * 32 + j * 4]);
    const int r3 = tid & 3;                        // matches reduce4 contract
    const int uw = u0 + r3;                        // u this lane finalizes
    const bool isglob = (tid & 8) != 0;
    const bool kill = (uw == 3) || (uw == 7);
    const int wr_off = (uw >> 5) * 36 + (uw & 31); // LDS h slot for uw

    if (tid < 144) *reinterpret_cast<float4*>(&hc[tid * 4]) = (float4){0,0,0,0};
    __syncthreads();

    float* rowp = xph + (size_t)blockIdx.x * (size_t)TT * UU;
    float xpv = rowp[uw];
    float xpn = rowp[UU + uw];

    auto step = [&](int t, int p) {
        float xpn2 = 0.f;
        if (t + 2 < TT) xpn2 = rowp[(size_t)(t + 2) * UU + uw];
        const float4* hb = reinterpret_cast<const float4*>(&hc[p * 288 + kk * 36]);
        float4 a0 = {0,0,0,0}, a1 = {0,0,0,0}, a2 = {0,0,0,0}, a3 = {0,0,0,0};
        #pragma unroll
        for (int j = 0; j < 8; ++j) {
            float4 hv = hb[j];
            fma4(a0, w[0][j], hv); fma4(a1, w[1][j], hv);
            fma4(a2, w[2][j], hv); fma4(a3, w[3][j], hv);
        }
        float s0 = (a0.x + a0.y) + (a0.z + a0.w);
        float s1 = (a1.x + a1.y) + (a1.z + a1.w);
        float s2 = (a2.x + a2.y) + (a2.z + a2.w);
        float s3 = (a3.x + a3.y) + (a3.z + a3.w);
        float D = reduce4(s0, s1, s2, s3, tid);
        float s = D + xpv;
        float hr = 1.0f - 2.0f / (__expf(2.0f * s) + 1.0f);
        if (isglob) {
            rowp[(size_t)t * UU + uw] = hr;                    // h_raw
        } else {
            hc[(p ^ 1) * 288 + wr_off] = kill ? 0.f : hr;      // masked carry
        }
        bar_lds();
        xpv = xpn; xpn = xpn2;
    };
    for (int t = 0; t < TT; t += 2) { step(t, 0); step(t + 1, 1); }
}

// ---------------- Kernel 3: readout + mask fix-up ----------------
// 512 thr: kk = tid&15 -> 16 chunks of 16 floats (K=256, stride 20);
// G = 32 groups own 4 o each. Reduce: quad,quad DPP + ror8 + ds_swizzle xor4.
__global__ __launch_bounds__(512, 2) void k_readout(
    const float* __restrict__ Wfc, const float* __restrict__ bfc,
    float* __restrict__ hraw, float* __restrict__ outR)
{
    __shared__ __align__(16) float hs[32 * 320];   // 32 rows x 16 chunks x 20
    const int tid = threadIdx.x;
    const int kk = tid & 15;
    const int G  = tid >> 4;                       // 0..31
    const int o0 = G * 4;
    float4 w[4][4];
    #pragma unroll
    for (int r = 0; r < 4; ++r)
        #pragma unroll
        for (int j = 0; j < 4; ++j)
            w[r][j] = *reinterpret_cast<const float4*>(
                &Wfc[(size_t)(o0 + r) * UU + kk * 16 + j * 4]);
    const int ow = o0 + (tid & 3);                 // matches reduce contract
    const float bias = bfc[ow];
    const bool writer = (tid & 12) == 0;
    const int ntiles = (BB * TT) / 32;             // 8192
    for (int tile = blockIdx.x; tile < ntiles; tile += gridDim.x) {
        const size_t rowbase = (size_t)tile * 32;
        const float4* hg = reinterpret_cast<const float4*>(hraw + rowbase * UU);
        #pragma unroll
        for (int i = 0; i < 4; ++i) {
            int v = tid + i * 512;                 // 0..2047 float4s
            int row = v >> 6, q = v & 63;
            float4 val = hg[v];
            *reinterpret_cast<float4*>(&hs[row * 320 + (q >> 2) * 20 + (q & 3) * 4]) = val;
        }
        __syncthreads();
        // raw values staged: zero killed units in the global hs output
        if (tid < 64) {
            int r = tid >> 1, c = (tid & 1) ? 7 : 3;
            hraw[(rowbase + r) * UU + c] = 0.f;
        }
        for (int r = 0; r < 32; ++r) {
            const float4* hrow = reinterpret_cast<const float4*>(&hs[r * 320 + kk * 20]);
            float4 a0 = {0,0,0,0}, a1 = {0,0,0,0}, a2 = {0,0,0,0}, a3 = {0,0,0,0};
            #pragma unroll
            for (int j = 0; j < 4; ++j) {
                float4 hv = hrow[j];
                fma4(a0, w[0][j], hv); fma4(a1, w[1][j], hv);
                fma4(a2, w[2][j], hv); fma4(a3, w[3][j], hv);
            }
            float s0 = (a0.x + a0.y) + (a0.z + a0.w);
            float s1 = (a1.x + a1.y) + (a1.z + a1.w);
            float s2 = (a2.x + a2.y) + (a2.z + a2.w);
            float s3 = (a3.x + a3.y) + (a3.z + a3.w);
            // stage1/2: resolve row bits 0,1 (same as reduce4, sans xor8)
            const bool e1 = (tid & 1), e2 = (tid & 2);
            float z0 = e1 ? s0 : s1;
            float z1 = e1 ? s2 : s3;
            float A0 = (e1 ? s1 : s0) + dpp_xor1(z0);
            float A1 = (e1 ? s3 : s2) + dpp_xor1(z1);
            float z2 = e2 ? A0 : A1;
            float C = (e2 ? A1 : A0) + dpp_xor2(z2);
            float C2 = C + dpp_xor8(C);            // + bit3 half
            float D  = C2 + swz_xor4(C2);          // + bit2 half (all 16 kk)
            if (writer) outR[(rowbase + r) * OO + ow] = D + bias;
        }
        __syncthreads();
    }
}

extern "C" void kernel_launch(void* const* d_in, const int* in_sizes, int n_in,
                              void* d_out, int out_size, void* d_ws, size_t ws_size,
                              hipStream_t stream) {
    const float* x   = (const float*)d_in[0];
    const float* Wih = (const float*)d_in[1];
    const float* Whh = (const float*)d_in[2];
    const float* bih = (const float*)d_in[3];
    const float* bhh = (const float*)d_in[4];
    const float* Wfc = (const float*)d_in[5];
    const float* bfc = (const float*)d_in[6];
    float* outR = (float*)d_out;                       // readouts [B,T,O]
    float* outH = outR + (size_t)BB * TT * OO;         // hs       [B,T,U]

    k_inproj<<<512, 512, 0, stream>>>(x, Wih, bih, bhh, outH);
    k_rnn<<<128, 512, 0, stream>>>(Whh, outH);
    k_readout<<<512, 512, 0, stream>>>(Wfc, bfc, outH, outR);
}